// Round 1
// baseline (769.355 us; speedup 1.0000x reference)
//
#include <hip/hip_runtime.h>
#include <math.h>

// AttnSum3d: x=input*mask[:,:,None]; S=X X^T (symmetric);
// w=softmax(S,axis=1) => attn_mean = 1/L exactly;
// out[b,0,d] = (1/L) sum_l x[b,l,d] * r[b,l],  r[l] = sum_m exp(S[l,m]-cmax[m])/csum[m].
// Two S passes (stats, rowsum) + tiny projection. fp32 VALU compute (no fp32 MFMA on CDNA4).

constexpr int NB = 16, NL = 2048, ND = 128;

// Transposed LDS tile [d][64 rows], f4-slot XOR-swizzled by (d&15) to fix staging-write conflicts.
__device__ __forceinline__ int swz(int d, int q, int lo) {
  return d * 64 + (((q ^ (d & 15)) << 2) | lo);
}

__device__ __forceinline__ void stage_tile(float* __restrict__ tile,
                                           const float* __restrict__ xb,
                                           const float* __restrict__ mb,
                                           int row0, int tid) {
#pragma unroll
  for (int k = 0; k < 8; ++k) {
    const int f = tid + 256 * k;
    const int row = f >> 5;       // 0..63 within tile
    const int dc4 = f & 31;       // float4 index along d
    const float4 v = *reinterpret_cast<const float4*>(xb + (row0 + row) * ND + (dc4 << 2));
    const float m = mb[row0 + row];
    const int q = row >> 2, lo = row & 3, d0 = dc4 << 2;
    tile[swz(d0 + 0, q, lo)] = v.x * m;
    tile[swz(d0 + 1, q, lo)] = v.y * m;
    tile[swz(d0 + 2, q, lo)] = v.z * m;
    tile[swz(d0 + 3, q, lo)] = v.w * m;
  }
}

// 64x64 tile GEMM fragment: thread (tr,tc) accumulates S[4tr+i][4tc+j], i,j in 0..3.
#define TILE_MM(At, Bt, tr, tc, acc)                                                         \
  do {                                                                                       \
    for (int d0 = 0; d0 < ND; d0 += 16) {                                                    \
      _Pragma("unroll")                                                                      \
      for (int k = 0; k < 16; ++k) {                                                         \
        const float4 a = *reinterpret_cast<const float4*>(&At[(d0 + k) * 64 + (((tr) ^ k) << 2)]); \
        const float4 b = *reinterpret_cast<const float4*>(&Bt[(d0 + k) * 64 + (((tc) ^ k) << 2)]); \
        acc[0][0] += a.x * b.x; acc[0][1] += a.x * b.y; acc[0][2] += a.x * b.z; acc[0][3] += a.x * b.w; \
        acc[1][0] += a.y * b.x; acc[1][1] += a.y * b.y; acc[1][2] += a.y * b.z; acc[1][3] += a.y * b.w; \
        acc[2][0] += a.z * b.x; acc[2][1] += a.z * b.y; acc[2][2] += a.z * b.z; acc[2][3] += a.z * b.w; \
        acc[3][0] += a.w * b.x; acc[3][1] += a.w * b.y; acc[3][2] += a.w * b.z; acc[3][3] += a.w * b.w; \
      }                                                                                      \
    }                                                                                        \
  } while (0)

// Pass 1: per-row (== per-column, S symmetric) online softmax stats.
__global__ __launch_bounds__(256) void k_stats(const float* __restrict__ x,
                                               const float* __restrict__ mask,
                                               float* __restrict__ cmax,
                                               float* __restrict__ crcp) {
  __shared__ float At[ND * 64];
  __shared__ float Bt[ND * 64];
  const int b = blockIdx.y;
  const int row0 = blockIdx.x * 64;
  const int tid = threadIdx.x;
  const int tc = tid & 15, tr = tid >> 4;
  const float* xb = x + b * NL * ND;
  const float* mb = mask + b * NL;

  stage_tile(At, xb, mb, row0, tid);

  float mx[4], sm[4];
#pragma unroll
  for (int i = 0; i < 4; ++i) { mx[i] = -INFINITY; sm[i] = 0.f; }

  for (int j0 = 0; j0 < NL; j0 += 64) {
    __syncthreads();
    stage_tile(Bt, xb, mb, j0, tid);
    __syncthreads();
    float acc[4][4] = {{0.f}};
    TILE_MM(At, Bt, tr, tc, acc);
#pragma unroll
    for (int i = 0; i < 4; ++i) {
#pragma unroll
      for (int j = 0; j < 4; ++j) {
        const float v = acc[i][j];
        const float nm = fmaxf(mx[i], v);
        sm[i] = sm[i] * __expf(mx[i] - nm) + __expf(v - nm);
        mx[i] = nm;
      }
    }
  }
  // reduce (mx,sm) across the 16 tc lanes (xor masks stay inside the 16-lane group)
#pragma unroll
  for (int i = 0; i < 4; ++i) {
    float m = mx[i], s = sm[i];
#pragma unroll
    for (int msk = 1; msk < 16; msk <<= 1) {
      const float m2 = __shfl_xor(m, msk);
      const float s2 = __shfl_xor(s, msk);
      const float nm = fmaxf(m, m2);
      s = s * __expf(m - nm) + s2 * __expf(m2 - nm);
      m = nm;
    }
    if (tc == 0) {
      const int row = row0 + 4 * tr + i;
      cmax[b * NL + row] = m;
      crcp[b * NL + row] = 1.0f / s;
    }
  }
}

// Pass 2: r[l] = sum_m exp(S[l,m]-cmax[m]) * crcp[m]; store r*mask for the projection.
__global__ __launch_bounds__(256) void k_rowsum(const float* __restrict__ x,
                                                const float* __restrict__ mask,
                                                const float* __restrict__ cmax,
                                                const float* __restrict__ crcp,
                                                float* __restrict__ rm) {
  __shared__ float At[ND * 64];
  __shared__ float Bt[ND * 64];
  const int b = blockIdx.y;
  const int row0 = blockIdx.x * 64;
  const int tid = threadIdx.x;
  const int tc = tid & 15, tr = tid >> 4;
  const float* xb = x + b * NL * ND;
  const float* mb = mask + b * NL;

  stage_tile(At, xb, mb, row0, tid);

  float racc[4] = {0.f, 0.f, 0.f, 0.f};

  for (int j0 = 0; j0 < NL; j0 += 64) {
    __syncthreads();
    stage_tile(Bt, xb, mb, j0, tid);
    __syncthreads();
    float acc[4][4] = {{0.f}};
    TILE_MM(At, Bt, tr, tc, acc);
#pragma unroll
    for (int j = 0; j < 4; ++j) {
      const int col = j0 + 4 * tc + j;
      const float cm = cmax[b * NL + col];
      const float ic = crcp[b * NL + col];
#pragma unroll
      for (int i = 0; i < 4; ++i)
        racc[i] += __expf(acc[i][j] - cm) * ic;  // arg <= 0, no overflow
    }
  }
#pragma unroll
  for (int i = 0; i < 4; ++i) {
    float s = racc[i];
#pragma unroll
    for (int msk = 1; msk < 16; msk <<= 1) s += __shfl_xor(s, msk);
    if (tc == 0) {
      const int row = row0 + 4 * tr + i;
      rm[b * NL + row] = s * mb[row];
    }
  }
}

// Pass 3: out[b,0,d] = (1/L) sum_l rm[b,l]*x[b,l,d]; attn_mean = 1/L (constant).
__global__ __launch_bounds__(1024) void k_out(const float* __restrict__ x,
                                              const float* __restrict__ rm,
                                              float* __restrict__ out) {
  const int b = blockIdx.x;
  const int tid = threadIdx.x;
  const int d = tid & (ND - 1);
  const int seg = tid >> 7;  // 0..7
  float acc = 0.f;
  for (int l = seg; l < NL; l += 8)
    acc += rm[b * NL + l] * x[(b * NL + l) * ND + d];
  __shared__ float red[8][ND];
  red[seg][d] = acc;
  __syncthreads();
  if (seg == 0) {
    float s = acc;
#pragma unroll
    for (int k = 1; k < 8; ++k) s += red[k][d];
    out[b * ND + d] = s * (1.0f / NL);
  }
  float* am = out + NB * ND;
  for (int i = tid; i < NL; i += 1024) am[b * NL + i] = 1.0f / NL;
}

extern "C" void kernel_launch(void* const* d_in, const int* in_sizes, int n_in,
                              void* d_out, int out_size, void* d_ws, size_t ws_size,
                              hipStream_t stream) {
  const float* x = (const float*)d_in[0];     // [16,2048,128] f32
  const float* mask = (const float*)d_in[1];  // [16,2048] f32
  float* out = (float*)d_out;                 // 2048 (out) + 32768 (attn_mean) f32
  float* cmax = (float*)d_ws;                 // [B*L]
  float* crcp = cmax + NB * NL;               // [B*L]
  float* rm = crcp + NB * NL;                 // [B*L]

  dim3 grid(NL / 64, NB);
  k_stats<<<grid, 256, 0, stream>>>(x, mask, cmax, crcp);
  k_rowsum<<<grid, 256, 0, stream>>>(x, mask, cmax, crcp, rm);
  k_out<<<NB, 1024, 0, stream>>>(x, rm, out);
}

// Round 2
// 189.388 us; speedup vs baseline: 4.0623x; 4.0623x over previous
//
#include <hip/hip_runtime.h>
#include <math.h>

// AttnSum3d via bf16-split MFMA:
//   X = x*mask;  Y = [bf16_hi(X) | bf16_lo(X)]  (L x 256 bf16, exact to ~2^-17)
//   S = Y Y^T (symmetric)  => softmax(S,axis=1) col stats == row stats
//   attn_mean = 1/L exactly;  out[b,0,d] = (1/L) sum_l X[l,d] * r[l],
//   r[l] = sum_m exp(S[l,m]-cmax[m]) / csum[m].
// Pass1 (k_stats): online (max,sum) per row.  Pass2 (k_rowsum): r.  Both are
// m97-structure bf16 GEMMs (128x128 tile, BK=128, 16x16x32 MFMA, gload_lds w16,
// LDS 16B-slot XOR swizzle by row&15 baked into Y's global layout).

constexpr int NB = 16, NL = 2048, ND = 128;
constexpr int ROWS_US = 256;  // ushorts per Y row (K_eff = 256 bf16)

typedef __attribute__((ext_vector_type(8))) short short8;
typedef __attribute__((ext_vector_type(4))) float f32x4;

__device__ __forceinline__ unsigned short f2bf(float f) {
  unsigned u = __builtin_bit_cast(unsigned, f);
  u += 0x7FFFu + ((u >> 16) & 1u);
  return (unsigned short)(u >> 16);
}
__device__ __forceinline__ float bf2f(unsigned short h) {
  unsigned u = ((unsigned)h) << 16;
  return __builtin_bit_cast(float, u);
}

__device__ __forceinline__ void stage16(const unsigned short* g, unsigned short* l) {
  __builtin_amdgcn_global_load_lds(
      (const __attribute__((address_space(1))) unsigned int*)g,
      (__attribute__((address_space(3))) unsigned int*)l, 16, 0, 0);
}

// Y layout: row r = b*NL+l occupies 512 B. Slot s (16 B = 8 bf16, k=8s..8s+7;
// s<16 -> hi half, s>=16 -> lo half) stored at slot position s ^ (r&15)
// (XOR stays within each 16-slot half). Fragment reads are then <=2-way.
__global__ __launch_bounds__(256) void k_prep(const float* __restrict__ x,
                                              const float* __restrict__ mask,
                                              unsigned short* __restrict__ Y) {
  const int gid = blockIdx.x * 256 + threadIdx.x;  // one float4 (4 d-elems)
  const int row = gid >> 5;
  const int dq = gid & 31;  // d = 4*dq
  const float4 v = reinterpret_cast<const float4*>(x)[gid];
  const float m = mask[row];
  const float f0 = v.x * m, f1 = v.y * m, f2 = v.z * m, f3 = v.w * m;
  const unsigned short h0 = f2bf(f0), h1 = f2bf(f1), h2 = f2bf(f2), h3 = f2bf(f3);
  const unsigned short e0 = f2bf(f0 - bf2f(h0)), e1 = f2bf(f1 - bf2f(h1)),
                       e2 = f2bf(f2 - bf2f(h2)), e3 = f2bf(f3 - bf2f(h3));
  unsigned short* Yr = Y + (size_t)row * ROWS_US;
  const int sx = dq >> 1, half8 = (dq & 1) * 4;
  const int posH = sx ^ (row & 15);
  const int posL = 16 + (sx ^ (row & 15));
  *reinterpret_cast<ushort4*>(Yr + posH * 8 + half8) = make_ushort4(h0, h1, h2, h3);
  *reinterpret_cast<ushort4*>(Yr + posL * 8 + half8) = make_ushort4(e0, e1, e2, e3);
}

// ---- pass 1: per-row online softmax stats over the block's column half ----
__global__ __launch_bounds__(256, 2) void k_stats(const unsigned short* __restrict__ Y,
                                                  float* __restrict__ pm,
                                                  float* __restrict__ ps) {
  __shared__ alignas(128) char lds[65536];
  unsigned short* At = (unsigned short*)lds;            // [128 rows][256 B]
  unsigned short* Bt = (unsigned short*)(lds + 32768);  // [128 cols][256 B]
  const int b = blockIdx.y;
  const int row0 = blockIdx.x * 128;
  const int jh = blockIdx.z;  // column half (1024 cols each)
  const int tid = threadIdx.x;
  const int lane = tid & 63, wave = tid >> 6;
  const int wr = wave >> 1, wc = wave & 1;
  const int lhi = lane >> 4, llo = lane & 15;
  const unsigned short* Yb = Y + (size_t)b * NL * ROWS_US;

  float mx[16], sm[16];
#pragma unroll
  for (int i = 0; i < 16; ++i) { mx[i] = -INFINITY; sm[i] = 0.f; }

  for (int jt = 0; jt < 8; ++jt) {
    const int j0 = jh * 1024 + jt * 128;
    f32x4 acc[4][4];
#pragma unroll
    for (int rs = 0; rs < 4; ++rs)
#pragma unroll
      for (int cs = 0; cs < 4; ++cs) acc[rs][cs] = f32x4{0.f, 0.f, 0.f, 0.f};

    for (int c = 0; c < 2; ++c) {  // BK=128 chunks of K=256
      __syncthreads();
#pragma unroll
      for (int it = 0; it < 8; ++it) {
        const int idx = tid + 256 * it;  // 0..2047 : 128 rows x 16 slots
        const int r = idx >> 4, s = idx & 15;
        stage16(Yb + (size_t)(row0 + r) * ROWS_US + c * 128 + s * 8, At + idx * 8);
        stage16(Yb + (size_t)(j0 + r) * ROWS_US + c * 128 + s * 8, Bt + idx * 8);
      }
      __syncthreads();
#pragma unroll
      for (int t = 0; t < 4; ++t) {  // 4 k-steps of 32
        const int sl = 4 * t + lhi;
        short8 af[4], bf[4];
#pragma unroll
        for (int q = 0; q < 4; ++q) {
          const int ra = 64 * wr + 16 * q + llo;
          af[q] = *(const short8*)(At + ra * 128 + ((sl ^ (ra & 15)) << 3));
          const int rb = 64 * wc + 16 * q + llo;
          bf[q] = *(const short8*)(Bt + rb * 128 + ((sl ^ (rb & 15)) << 3));
        }
#pragma unroll
        for (int rs = 0; rs < 4; ++rs)
#pragma unroll
          for (int cs = 0; cs < 4; ++cs)
            acc[rs][cs] = __builtin_amdgcn_mfma_f32_16x16x32_bf16(af[rs], bf[cs], acc[rs][cs], 0, 0, 0);
      }
    }
    // online (max,sum) update; C layout: col=lane&15, row=(lane>>4)*4+reg
#pragma unroll
    for (int rs = 0; rs < 4; ++rs)
#pragma unroll
      for (int rg = 0; rg < 4; ++rg) {
        const int i = rs * 4 + rg;
        const float v0 = acc[rs][0][rg], v1 = acc[rs][1][rg];
        const float v2 = acc[rs][2][rg], v3 = acc[rs][3][rg];
        const float tmax = fmaxf(fmaxf(v0, v1), fmaxf(v2, v3));
        const float nm = fmaxf(mx[i], tmax);
        sm[i] = sm[i] * __expf(mx[i] - nm) + __expf(v0 - nm) + __expf(v1 - nm) +
                __expf(v2 - nm) + __expf(v3 - nm);
        mx[i] = nm;
      }
  }
  // reduce across the 16 column lanes of each group
#pragma unroll
  for (int i = 0; i < 16; ++i) {
    float m = mx[i], s = sm[i];
#pragma unroll
    for (int k = 1; k < 16; k <<= 1) {
      const float m2 = __shfl_xor(m, k);
      const float s2 = __shfl_xor(s, k);
      const float nm = fmaxf(m, m2);
      s = s * __expf(m - nm) + s2 * __expf(m2 - nm);
      m = nm;
    }
    mx[i] = m; sm[i] = s;
  }
  __syncthreads();
  float* sc = (float*)lds;  // [2 wc][128 rows][2]
  if (llo == 0) {
#pragma unroll
    for (int rs = 0; rs < 4; ++rs)
#pragma unroll
      for (int rg = 0; rg < 4; ++rg) {
        const int rowl = 64 * wr + 16 * rs + 4 * lhi + rg;
        sc[(wc * 128 + rowl) * 2 + 0] = mx[rs * 4 + rg];
        sc[(wc * 128 + rowl) * 2 + 1] = sm[rs * 4 + rg];
      }
  }
  __syncthreads();
  if (tid < 128) {
    const float m0 = sc[tid * 2 + 0], s0 = sc[tid * 2 + 1];
    const float m1 = sc[(128 + tid) * 2 + 0], s1 = sc[(128 + tid) * 2 + 1];
    const float nm = fmaxf(m0, m1);
    const float s = s0 * __expf(m0 - nm) + s1 * __expf(m1 - nm);
    const size_t o = ((size_t)jh * NB + b) * NL + row0 + tid;
    pm[o] = nm;
    ps[o] = s;
  }
}

__global__ __launch_bounds__(256) void k_comb(const float* __restrict__ pm,
                                              const float* __restrict__ ps,
                                              float* __restrict__ cmax,
                                              float* __restrict__ crcp) {
  const int i = blockIdx.x * 256 + threadIdx.x;
  const float m0 = pm[i], m1 = pm[NB * NL + i];
  const float nm = fmaxf(m0, m1);
  const float s = ps[i] * __expf(m0 - nm) + ps[NB * NL + i] * __expf(m1 - nm);
  cmax[i] = nm;
  crcp[i] = 1.0f / s;
}

// ---- pass 2: r[l] partials over the block's column half ----
__global__ __launch_bounds__(256, 2) void k_rowsum(const unsigned short* __restrict__ Y,
                                                   const float* __restrict__ cmax,
                                                   const float* __restrict__ crcp,
                                                   float* __restrict__ rp) {
  __shared__ alignas(128) char lds[65536];
  unsigned short* At = (unsigned short*)lds;
  unsigned short* Bt = (unsigned short*)(lds + 32768);
  const int b = blockIdx.y;
  const int row0 = blockIdx.x * 128;
  const int jh = blockIdx.z;
  const int tid = threadIdx.x;
  const int lane = tid & 63, wave = tid >> 6;
  const int wr = wave >> 1, wc = wave & 1;
  const int lhi = lane >> 4, llo = lane & 15;
  const unsigned short* Yb = Y + (size_t)b * NL * ROWS_US;

  float racc[16];
#pragma unroll
  for (int i = 0; i < 16; ++i) racc[i] = 0.f;

  for (int jt = 0; jt < 8; ++jt) {
    const int j0 = jh * 1024 + jt * 128;
    f32x4 acc[4][4];
#pragma unroll
    for (int rs = 0; rs < 4; ++rs)
#pragma unroll
      for (int cs = 0; cs < 4; ++cs) acc[rs][cs] = f32x4{0.f, 0.f, 0.f, 0.f};

    for (int c = 0; c < 2; ++c) {
      __syncthreads();
#pragma unroll
      for (int it = 0; it < 8; ++it) {
        const int idx = tid + 256 * it;
        const int r = idx >> 4, s = idx & 15;
        stage16(Yb + (size_t)(row0 + r) * ROWS_US + c * 128 + s * 8, At + idx * 8);
        stage16(Yb + (size_t)(j0 + r) * ROWS_US + c * 128 + s * 8, Bt + idx * 8);
      }
      __syncthreads();
#pragma unroll
      for (int t = 0; t < 4; ++t) {
        const int sl = 4 * t + lhi;
        short8 af[4], bf[4];
#pragma unroll
        for (int q = 0; q < 4; ++q) {
          const int ra = 64 * wr + 16 * q + llo;
          af[q] = *(const short8*)(At + ra * 128 + ((sl ^ (ra & 15)) << 3));
          const int rb = 64 * wc + 16 * q + llo;
          bf[q] = *(const short8*)(Bt + rb * 128 + ((sl ^ (rb & 15)) << 3));
        }
#pragma unroll
        for (int rs = 0; rs < 4; ++rs)
#pragma unroll
          for (int cs = 0; cs < 4; ++cs)
            acc[rs][cs] = __builtin_amdgcn_mfma_f32_16x16x32_bf16(af[rs], bf[cs], acc[rs][cs], 0, 0, 0);
      }
    }
    float cm[4], cr[4];
#pragma unroll
    for (int cs = 0; cs < 4; ++cs) {
      const int col = j0 + 64 * wc + 16 * cs + llo;
      cm[cs] = cmax[b * NL + col];
      cr[cs] = crcp[b * NL + col];
    }
#pragma unroll
    for (int rs = 0; rs < 4; ++rs)
#pragma unroll
      for (int rg = 0; rg < 4; ++rg) {
        float t = 0.f;
#pragma unroll
        for (int cs = 0; cs < 4; ++cs)
          t += __expf(acc[rs][cs][rg] - cm[cs]) * cr[cs];
        racc[rs * 4 + rg] += t;
      }
  }
#pragma unroll
  for (int i = 0; i < 16; ++i) {
    float s = racc[i];
#pragma unroll
    for (int k = 1; k < 16; k <<= 1) s += __shfl_xor(s, k);
    racc[i] = s;
  }
  __syncthreads();
  float* sc = (float*)lds;  // [2 wc][128 rows]
  if (llo == 0) {
#pragma unroll
    for (int rs = 0; rs < 4; ++rs)
#pragma unroll
      for (int rg = 0; rg < 4; ++rg) {
        const int rowl = 64 * wr + 16 * rs + 4 * lhi + rg;
        sc[wc * 128 + rowl] = racc[rs * 4 + rg];
      }
  }
  __syncthreads();
  if (tid < 128)
    rp[((size_t)jh * NB + b) * NL + row0 + tid] = sc[tid] + sc[128 + tid];
}

// ---- pass 3: out[b,0,d] = (1/L) sum_l (r0+r1)*mask * x ; attn_mean = 1/L ----
__global__ __launch_bounds__(1024) void k_out(const float* __restrict__ x,
                                              const float* __restrict__ mask,
                                              const float* __restrict__ rp,
                                              float* __restrict__ out) {
  const int b = blockIdx.x;
  const int tid = threadIdx.x;
  const int d = tid & (ND - 1);
  const int seg = tid >> 7;  // 0..7
  float acc = 0.f;
  for (int l = seg; l < NL; l += 8) {
    const float w = (rp[b * NL + l] + rp[NB * NL + b * NL + l]) * mask[b * NL + l];
    acc += w * x[((size_t)b * NL + l) * ND + d];
  }
  __shared__ float red[8][ND];
  red[seg][d] = acc;
  __syncthreads();
  if (seg == 0) {
    float s = acc;
#pragma unroll
    for (int k = 1; k < 8; ++k) s += red[k][d];
    out[b * ND + d] = s * (1.0f / NL);
  }
  float* am = out + NB * ND;
  for (int i = tid; i < NL; i += 1024) am[b * NL + i] = 1.0f / NL;
}

extern "C" void kernel_launch(void* const* d_in, const int* in_sizes, int n_in,
                              void* d_out, int out_size, void* d_ws, size_t ws_size,
                              hipStream_t stream) {
  const float* x = (const float*)d_in[0];     // [16,2048,128] f32
  const float* mask = (const float*)d_in[1];  // [16,2048] f32
  float* out = (float*)d_out;

  unsigned short* Y = (unsigned short*)d_ws;  // 16.8 MB
  float* fws = (float*)(Y + (size_t)NB * NL * ROWS_US);
  float* pm = fws;                  // [2][NB*NL]
  float* ps = pm + 2 * NB * NL;     // [2][NB*NL]
  float* cmax = ps + 2 * NB * NL;   // [NB*NL]
  float* crcp = cmax + NB * NL;     // [NB*NL]
  float* rp = crcp + NB * NL;       // [2][NB*NL]

  k_prep<<<dim3(NB * NL * ND / 4 / 256), 256, 0, stream>>>(x, mask, Y);
  dim3 g(NL / 128, NB, 2);
  k_stats<<<g, 256, 0, stream>>>(Y, pm, ps);
  k_comb<<<dim3(NB * NL / 256), 256, 0, stream>>>(pm, ps, cmax, crcp);
  k_rowsum<<<g, 256, 0, stream>>>(Y, cmax, crcp, rp);
  k_out<<<NB, 1024, 0, stream>>>(x, mask, rp, out);
}

// Round 3
// 112.878 us; speedup vs baseline: 6.8158x; 1.6778x over previous
//
#include <hip/hip_runtime.h>
#include <math.h>

// AttnSum3d via bf16-split MFMA:
//   X = x*mask;  Y = [bf16_hi(X) | bf16_lo(X)]  (L x 256 bf16, exact to ~2^-17)
//   S = Y Y^T (symmetric)  => softmax(S,axis=1) col stats == row stats
//   attn_mean = 1/L exactly;  out[b,0,d] = (1/L) sum_l X[l,d] * r[l],
//   r[l] = sum_m exp(S[l,m]-cmax[m]) / csum[m].
// Pass1 (k_stats): online (max,sum) per row.  Pass2 (k_rowsum): r.  Both are
// m97-structure bf16 GEMMs (128x128 tile, BK=128, 16x16x32 MFMA, gload_lds w16,
// LDS 16B-slot XOR swizzle by row&15 baked into Y's global layout).
// Pass3 split into 256-block partial reduction + tiny finalize (R2: old 16-block
// k_out was 86us at 1.3% HBM).

constexpr int NB = 16, NL = 2048, ND = 128;
constexpr int ROWS_US = 256;  // ushorts per Y row (K_eff = 256 bf16)

typedef __attribute__((ext_vector_type(8))) short short8;
typedef __attribute__((ext_vector_type(4))) float f32x4;

__device__ __forceinline__ unsigned short f2bf(float f) {
  unsigned u = __builtin_bit_cast(unsigned, f);
  u += 0x7FFFu + ((u >> 16) & 1u);
  return (unsigned short)(u >> 16);
}
__device__ __forceinline__ float bf2f(unsigned short h) {
  unsigned u = ((unsigned)h) << 16;
  return __builtin_bit_cast(float, u);
}

__device__ __forceinline__ void stage16(const unsigned short* g, unsigned short* l) {
  __builtin_amdgcn_global_load_lds(
      (const __attribute__((address_space(1))) unsigned int*)g,
      (__attribute__((address_space(3))) unsigned int*)l, 16, 0, 0);
}

// Y layout: row r = b*NL+l occupies 512 B. Slot s (16 B = 8 bf16, k=8s..8s+7;
// s<16 -> hi half, s>=16 -> lo half) stored at slot position s ^ (r&15)
// (XOR stays within each 16-slot half). Fragment reads are then <=2-way.
__global__ __launch_bounds__(256) void k_prep(const float* __restrict__ x,
                                              const float* __restrict__ mask,
                                              unsigned short* __restrict__ Y) {
  const int gid = blockIdx.x * 256 + threadIdx.x;  // one float4 (4 d-elems)
  const int row = gid >> 5;
  const int dq = gid & 31;  // d = 4*dq
  const float4 v = reinterpret_cast<const float4*>(x)[gid];
  const float m = mask[row];
  const float f0 = v.x * m, f1 = v.y * m, f2 = v.z * m, f3 = v.w * m;
  const unsigned short h0 = f2bf(f0), h1 = f2bf(f1), h2 = f2bf(f2), h3 = f2bf(f3);
  const unsigned short e0 = f2bf(f0 - bf2f(h0)), e1 = f2bf(f1 - bf2f(h1)),
                       e2 = f2bf(f2 - bf2f(h2)), e3 = f2bf(f3 - bf2f(h3));
  unsigned short* Yr = Y + (size_t)row * ROWS_US;
  const int sx = dq >> 1, half8 = (dq & 1) * 4;
  const int posH = sx ^ (row & 15);
  const int posL = 16 + (sx ^ (row & 15));
  *reinterpret_cast<ushort4*>(Yr + posH * 8 + half8) = make_ushort4(h0, h1, h2, h3);
  *reinterpret_cast<ushort4*>(Yr + posL * 8 + half8) = make_ushort4(e0, e1, e2, e3);
}

// ---- pass 1: per-row online softmax stats over the block's column half ----
__global__ __launch_bounds__(256, 2) void k_stats(const unsigned short* __restrict__ Y,
                                                  float* __restrict__ pm,
                                                  float* __restrict__ ps) {
  __shared__ alignas(128) char lds[65536];
  unsigned short* At = (unsigned short*)lds;            // [128 rows][256 B]
  unsigned short* Bt = (unsigned short*)(lds + 32768);  // [128 cols][256 B]
  const int b = blockIdx.y;
  const int row0 = blockIdx.x * 128;
  const int jh = blockIdx.z;  // column half (1024 cols each)
  const int tid = threadIdx.x;
  const int lane = tid & 63, wave = tid >> 6;
  const int wr = wave >> 1, wc = wave & 1;
  const int lhi = lane >> 4, llo = lane & 15;
  const unsigned short* Yb = Y + (size_t)b * NL * ROWS_US;

  float mx[16], sm[16];
#pragma unroll
  for (int i = 0; i < 16; ++i) { mx[i] = -INFINITY; sm[i] = 0.f; }

  for (int jt = 0; jt < 8; ++jt) {
    const int j0 = jh * 1024 + jt * 128;
    f32x4 acc[4][4];
#pragma unroll
    for (int rs = 0; rs < 4; ++rs)
#pragma unroll
      for (int cs = 0; cs < 4; ++cs) acc[rs][cs] = f32x4{0.f, 0.f, 0.f, 0.f};

    for (int c = 0; c < 2; ++c) {  // BK=128 chunks of K=256
      __syncthreads();
#pragma unroll
      for (int it = 0; it < 8; ++it) {
        const int idx = tid + 256 * it;  // 0..2047 : 128 rows x 16 slots
        const int r = idx >> 4, s = idx & 15;
        stage16(Yb + (size_t)(row0 + r) * ROWS_US + c * 128 + s * 8, At + idx * 8);
        stage16(Yb + (size_t)(j0 + r) * ROWS_US + c * 128 + s * 8, Bt + idx * 8);
      }
      __syncthreads();
#pragma unroll
      for (int t = 0; t < 4; ++t) {  // 4 k-steps of 32
        const int sl = 4 * t + lhi;
        short8 af[4], bf[4];
#pragma unroll
        for (int q = 0; q < 4; ++q) {
          const int ra = 64 * wr + 16 * q + llo;
          af[q] = *(const short8*)(At + ra * 128 + ((sl ^ (ra & 15)) << 3));
          const int rb = 64 * wc + 16 * q + llo;
          bf[q] = *(const short8*)(Bt + rb * 128 + ((sl ^ (rb & 15)) << 3));
        }
#pragma unroll
        for (int rs = 0; rs < 4; ++rs)
#pragma unroll
          for (int cs = 0; cs < 4; ++cs)
            acc[rs][cs] = __builtin_amdgcn_mfma_f32_16x16x32_bf16(af[rs], bf[cs], acc[rs][cs], 0, 0, 0);
      }
    }
    // online (max,sum) update; C layout: col=lane&15, row=(lane>>4)*4+reg
#pragma unroll
    for (int rs = 0; rs < 4; ++rs)
#pragma unroll
      for (int rg = 0; rg < 4; ++rg) {
        const int i = rs * 4 + rg;
        const float v0 = acc[rs][0][rg], v1 = acc[rs][1][rg];
        const float v2 = acc[rs][2][rg], v3 = acc[rs][3][rg];
        const float tmax = fmaxf(fmaxf(v0, v1), fmaxf(v2, v3));
        const float nm = fmaxf(mx[i], tmax);
        sm[i] = sm[i] * __expf(mx[i] - nm) + __expf(v0 - nm) + __expf(v1 - nm) +
                __expf(v2 - nm) + __expf(v3 - nm);
        mx[i] = nm;
      }
  }
  // reduce across the 16 column lanes of each group
#pragma unroll
  for (int i = 0; i < 16; ++i) {
    float m = mx[i], s = sm[i];
#pragma unroll
    for (int k = 1; k < 16; k <<= 1) {
      const float m2 = __shfl_xor(m, k);
      const float s2 = __shfl_xor(s, k);
      const float nm = fmaxf(m, m2);
      s = s * __expf(m - nm) + s2 * __expf(m2 - nm);
      m = nm;
    }
    mx[i] = m; sm[i] = s;
  }
  __syncthreads();
  float* sc = (float*)lds;  // [2 wc][128 rows][2]
  if (llo == 0) {
#pragma unroll
    for (int rs = 0; rs < 4; ++rs)
#pragma unroll
      for (int rg = 0; rg < 4; ++rg) {
        const int rowl = 64 * wr + 16 * rs + 4 * lhi + rg;
        sc[(wc * 128 + rowl) * 2 + 0] = mx[rs * 4 + rg];
        sc[(wc * 128 + rowl) * 2 + 1] = sm[rs * 4 + rg];
      }
  }
  __syncthreads();
  if (tid < 128) {
    const float m0 = sc[tid * 2 + 0], s0 = sc[tid * 2 + 1];
    const float m1 = sc[(128 + tid) * 2 + 0], s1 = sc[(128 + tid) * 2 + 1];
    const float nm = fmaxf(m0, m1);
    const float s = s0 * __expf(m0 - nm) + s1 * __expf(m1 - nm);
    const size_t o = ((size_t)jh * NB + b) * NL + row0 + tid;
    pm[o] = nm;
    ps[o] = s;
  }
}

__global__ __launch_bounds__(256) void k_comb(const float* __restrict__ pm,
                                              const float* __restrict__ ps,
                                              float* __restrict__ cmax,
                                              float* __restrict__ crcp) {
  const int i = blockIdx.x * 256 + threadIdx.x;
  const float m0 = pm[i], m1 = pm[NB * NL + i];
  const float nm = fmaxf(m0, m1);
  const float s = ps[i] * __expf(m0 - nm) + ps[NB * NL + i] * __expf(m1 - nm);
  cmax[i] = nm;
  crcp[i] = 1.0f / s;
}

// ---- pass 2: r[l] partials over the block's column half ----
__global__ __launch_bounds__(256, 2) void k_rowsum(const unsigned short* __restrict__ Y,
                                                   const float* __restrict__ cmax,
                                                   const float* __restrict__ crcp,
                                                   float* __restrict__ rp) {
  __shared__ alignas(128) char lds[65536];
  unsigned short* At = (unsigned short*)lds;
  unsigned short* Bt = (unsigned short*)(lds + 32768);
  const int b = blockIdx.y;
  const int row0 = blockIdx.x * 128;
  const int jh = blockIdx.z;
  const int tid = threadIdx.x;
  const int lane = tid & 63, wave = tid >> 6;
  const int wr = wave >> 1, wc = wave & 1;
  const int lhi = lane >> 4, llo = lane & 15;
  const unsigned short* Yb = Y + (size_t)b * NL * ROWS_US;

  float racc[16];
#pragma unroll
  for (int i = 0; i < 16; ++i) racc[i] = 0.f;

  for (int jt = 0; jt < 8; ++jt) {
    const int j0 = jh * 1024 + jt * 128;
    f32x4 acc[4][4];
#pragma unroll
    for (int rs = 0; rs < 4; ++rs)
#pragma unroll
      for (int cs = 0; cs < 4; ++cs) acc[rs][cs] = f32x4{0.f, 0.f, 0.f, 0.f};

    for (int c = 0; c < 2; ++c) {
      __syncthreads();
#pragma unroll
      for (int it = 0; it < 8; ++it) {
        const int idx = tid + 256 * it;
        const int r = idx >> 4, s = idx & 15;
        stage16(Yb + (size_t)(row0 + r) * ROWS_US + c * 128 + s * 8, At + idx * 8);
        stage16(Yb + (size_t)(j0 + r) * ROWS_US + c * 128 + s * 8, Bt + idx * 8);
      }
      __syncthreads();
#pragma unroll
      for (int t = 0; t < 4; ++t) {
        const int sl = 4 * t + lhi;
        short8 af[4], bf[4];
#pragma unroll
        for (int q = 0; q < 4; ++q) {
          const int ra = 64 * wr + 16 * q + llo;
          af[q] = *(const short8*)(At + ra * 128 + ((sl ^ (ra & 15)) << 3));
          const int rb = 64 * wc + 16 * q + llo;
          bf[q] = *(const short8*)(Bt + rb * 128 + ((sl ^ (rb & 15)) << 3));
        }
#pragma unroll
        for (int rs = 0; rs < 4; ++rs)
#pragma unroll
          for (int cs = 0; cs < 4; ++cs)
            acc[rs][cs] = __builtin_amdgcn_mfma_f32_16x16x32_bf16(af[rs], bf[cs], acc[rs][cs], 0, 0, 0);
      }
    }
    float cm[4], cr[4];
#pragma unroll
    for (int cs = 0; cs < 4; ++cs) {
      const int col = j0 + 64 * wc + 16 * cs + llo;
      cm[cs] = cmax[b * NL + col];
      cr[cs] = crcp[b * NL + col];
    }
#pragma unroll
    for (int rs = 0; rs < 4; ++rs)
#pragma unroll
      for (int rg = 0; rg < 4; ++rg) {
        float t = 0.f;
#pragma unroll
        for (int cs = 0; cs < 4; ++cs)
          t += __expf(acc[rs][cs][rg] - cm[cs]) * cr[cs];
        racc[rs * 4 + rg] += t;
      }
  }
#pragma unroll
  for (int i = 0; i < 16; ++i) {
    float s = racc[i];
#pragma unroll
    for (int k = 1; k < 16; k <<= 1) s += __shfl_xor(s, k);
    racc[i] = s;
  }
  __syncthreads();
  float* sc = (float*)lds;  // [2 wc][128 rows]
  if (llo == 0) {
#pragma unroll
    for (int rs = 0; rs < 4; ++rs)
#pragma unroll
      for (int rg = 0; rg < 4; ++rg) {
        const int rowl = 64 * wr + 16 * rs + 4 * lhi + rg;
        sc[wc * 128 + rowl] = racc[rs * 4 + rg];
      }
  }
  __syncthreads();
  if (tid < 128)
    rp[((size_t)jh * NB + b) * NL + row0 + tid] = sc[tid] + sc[128 + tid];
}

// ---- pass 3a: per-(b,seg) partial of sum_l w[l]*x[l,:] (256 blocks) ----
__global__ __launch_bounds__(256) void k_outp(const float* __restrict__ x,
                                              const float* __restrict__ mask,
                                              const float* __restrict__ rp,
                                              float* __restrict__ partial) {
  const int b = blockIdx.y;
  const int seg = blockIdx.x;  // 16 segments of 128 rows
  const int tid = threadIdx.x;
  const int dq = tid & 31;     // float4 index along d
  const int rg = tid >> 5;     // 0..7
  const int l0 = seg * 128;
  float4 acc = make_float4(0.f, 0.f, 0.f, 0.f);
#pragma unroll 4
  for (int i = 0; i < 16; ++i) {
    const int l = l0 + 8 * i + rg;
    const float w = (rp[b * NL + l] + rp[NB * NL + b * NL + l]) * mask[b * NL + l];
    const float4 v = *reinterpret_cast<const float4*>(x + ((size_t)b * NL + l) * ND + 4 * dq);
    acc.x += w * v.x; acc.y += w * v.y; acc.z += w * v.z; acc.w += w * v.w;
  }
  __shared__ float4 red[8][32];
  red[rg][dq] = acc;
  __syncthreads();
  if (rg == 0) {
    float4 s = acc;
#pragma unroll
    for (int k = 1; k < 8; ++k) {
      const float4 t = red[k][dq];
      s.x += t.x; s.y += t.y; s.z += t.z; s.w += t.w;
    }
    *reinterpret_cast<float4*>(partial + ((size_t)(b * 16 + seg)) * ND + 4 * dq) = s;
  }
}

// ---- pass 3b: finalize out + constant attn_mean fill (32 blocks) ----
__global__ __launch_bounds__(1024) void k_fin(const float* __restrict__ partial,
                                              float* __restrict__ out) {
  const int gid = blockIdx.x * 1024 + threadIdx.x;  // 0..32767
  if (gid < NB * ND) {
    const int b = gid >> 7, d = gid & (ND - 1);
    float s = 0.f;
#pragma unroll
    for (int k = 0; k < 16; ++k) s += partial[(size_t)(b * 16 + k) * ND + d];
    out[gid] = s * (1.0f / NL);
  }
  out[NB * ND + gid] = 1.0f / NL;  // attn_mean == 1/L exactly
}

extern "C" void kernel_launch(void* const* d_in, const int* in_sizes, int n_in,
                              void* d_out, int out_size, void* d_ws, size_t ws_size,
                              hipStream_t stream) {
  const float* x = (const float*)d_in[0];     // [16,2048,128] f32
  const float* mask = (const float*)d_in[1];  // [16,2048] f32
  float* out = (float*)d_out;

  unsigned short* Y = (unsigned short*)d_ws;  // 16.8 MB
  float* fws = (float*)(Y + (size_t)NB * NL * ROWS_US);
  float* pm = fws;                  // [2][NB*NL]
  float* ps = pm + 2 * NB * NL;     // [2][NB*NL]
  float* cmax = ps + 2 * NB * NL;   // [NB*NL]
  float* crcp = cmax + NB * NL;     // [NB*NL]
  float* rp = crcp + NB * NL;       // [2][NB*NL]
  float* partial = rp + 2 * NB * NL;  // [NB*16*ND]

  k_prep<<<dim3(NB * NL * ND / 4 / 256), 256, 0, stream>>>(x, mask, Y);
  dim3 g(NL / 128, NB, 2);
  k_stats<<<g, 256, 0, stream>>>(Y, pm, ps);
  k_comb<<<dim3(NB * NL / 256), 256, 0, stream>>>(pm, ps, cmax, crcp);
  k_rowsum<<<g, 256, 0, stream>>>(Y, cmax, crcp, rp);
  k_outp<<<dim3(16, NB), 256, 0, stream>>>(x, mask, rp, partial);
  k_fin<<<32, 1024, 0, stream>>>(partial, out);
}